// Round 14
// baseline (143.841 us; speedup 1.0000x reference)
//
#include <hip/hip_runtime.h>
#include <math.h>

// CapsuleLayer dynamic routing, MI355X — R14: prepack BOTH operands to
// fragment order once, then 3 fully-coalesced c-fused MFMA passes.
// B=128, R=4096, IN=16, OUT=32, C=2, 3 routing iterations.
//
// Evidence: R7(LDS W) == R13(global W) ~20us/pass -> pass cost invariant to
// W path; the shared term is the strided x-gather (16B/lane from 256KB-
// strided lines) + 2x c-duplication. R14: xq = x transposed to B-frag order
// (8B/lane, 512B/wave contiguous, f16); pass fuses both c (1 x-record feeds
// 4 MFMA). Zero LDS, zero barriers in passes.
// Math (proven R5+): logits linear in running v-sum; it0 softmax uniform.
// k-slot safety (HW-verified R6+): both mfma operands put i=4*(L>>4)+j in
// elements 0..3, zeros 4..7. C/D layout (m89): col=lane&15, row=4g+reg.
// f16 precision proven (absmax 0.0039 < threshold 0.0124).
#define CB     128
#define CR     4096
#define CIN    16
#define COUT   32
#define CCAP   2
#define RC     8             // r rows per pass chunk (c-fused)
#define NRCH2  (CR / RC)     // 512 chunks
#define EPSF   1e-12f

typedef _Float16 h8  __attribute__((ext_vector_type(8)));
typedef _Float16 h4t __attribute__((ext_vector_type(4)));
typedef float    f4  __attribute__((ext_vector_type(4)));

// ---------------------------------------------------------------------------
// prepack W (proven R13): wp[(c*CR + r)*64 + L] = h8 { W[c][r][4g+j][m],
//   W[c][r][4g+j][16+m] }  (j=0..3), g=L>>4, m=L&15.
// ---------------------------------------------------------------------------
__global__ __launch_bounds__(256) void caps_prepw_kernel(
    const float* __restrict__ w, h8* __restrict__ wp)
{
  const int blk = (int)blockIdx.x;
  const int c   = blk >> 10;
  const int r0  = (blk & 1023) * 4;
  const int t   = (int)threadIdx.x;

  __shared__ __align__(16) float Wl[4 * 512];   // 8 KB
  {
    const float4* src = (const float4*)(w + ((size_t)c * CR + r0) * 512);
    ((float4*)Wl)[t]       = src[t];
    ((float4*)Wl)[t + 256] = src[t + 256];
  }
  __syncthreads();

  const int rr = t >> 6;        // 0..3
  const int L  = t & 63;
  const int g  = L >> 4, m = L & 15;
  h8 v;
#pragma unroll
  for (int j = 0; j < 4; ++j) {
    v[j]     = (_Float16)Wl[rr * 512 + (4 * g + j) * 32 + m];
    v[4 + j] = (_Float16)Wl[rr * 512 + (4 * g + j) * 32 + 16 + m];
  }
  wp[((size_t)c * CR + r0 + rr) * 64 + L] = v;
}

// ---------------------------------------------------------------------------
// prepack x -> B-fragment order, f16:
//   xq[(r*8 + wv)*64 + g*16 + m] = h4 { x[wv*16+m][r][4g+j] }  j=0..3
// Thread G handles one (r, wv, g) and m=0..15: reads 16 float4 (a g-quad of
// threads consumes full 64B lines), writes 16 h4 = 128 B contiguous.
// grid = 512 x 256 (G = 0..131071: g=G&3, wv=(G>>2)&7, r=G>>5).
// ---------------------------------------------------------------------------
__global__ __launch_bounds__(256) void caps_prepx_kernel(
    const float* __restrict__ x, h4t* __restrict__ xq)
{
  const int G  = (int)(blockIdx.x * 256 + threadIdx.x);
  const int g  = G & 3;
  const int wv = (G >> 2) & 7;
  const int r  = G >> 5;

  h4t recs[16];
#pragma unroll
  for (int m = 0; m < 16; ++m) {
    float4 xf = *(const float4*)(x + ((size_t)(wv * 16 + m) * CR + r) * CIN + 4 * g);
    recs[m] = h4t{(_Float16)xf.x, (_Float16)xf.y, (_Float16)xf.z, (_Float16)xf.w};
  }
  h4t* dst = xq + ((size_t)(r * 8 + wv)) * 64 + g * 16;
#pragma unroll
  for (int m = 0; m < 16; ++m) dst[m] = recs[m];
}

// direct fragment-order partial stores (coalesced, no barriers). Proven.
__device__ __forceinline__ void store_partials(float* __restrict__ partialA,
                                               float* __restrict__ partialE,
                                               const float* accA, const float* accB,
                                               float esum, int c, int rch,
                                               int t, int g, int b)
{
  float4 a4 = {accA[0], accA[1], accA[2], accA[3]};
  float4 b4 = {accB[0], accB[1], accB[2], accB[3]};
  float* dst = partialA + ((size_t)(c * NRCH2 + rch)) * 4096 + (size_t)t * 8;
  *(float4*)dst = a4;
  *(float4*)(dst + 4) = b4;
  if (g == 0) partialE[((size_t)(c * NRCH2 + rch)) * CB + b] = esum;
}

// ---------------------------------------------------------------------------
// pass: grid = NRCH2 = 512 blocks x 512 threads, BOTH c per block.
// Zero LDS, zero barriers. Per ri: 1 xq h4 (8B) + 2 wp h8 (16B) loads,
// 4 mfma, 2x(dot + 2 shfl + exp), 16 acc FMA.
// ---------------------------------------------------------------------------
__global__ __launch_bounds__(512, 4) void caps_pass_kernel(
    const h4t* __restrict__ xq, const h8* __restrict__ wp,
    const float* __restrict__ vsum,
    float* __restrict__ partialA, float* __restrict__ partialE,
    int uniform)
{
  const int rch = (int)blockIdx.x;      // 0..511
  const int r0  = rch * RC;
  const int t   = (int)threadIdx.x;
  const int wv  = t >> 6, L = t & 63, g = L >> 4, m = L & 15;
  const int b   = wv * 16 + m;

  const h4t* xrow  = xq + ((size_t)(r0 * 8 + wv)) * 64 + L;
  const h8*  w0row = wp + ((size_t)0 * CR + r0) * 64 + L;
  const h8*  w1row = wp + ((size_t)1 * CR + r0) * 64 + L;

  float4 vA0 = {0.f,0.f,0.f,0.f}, vB0 = {0.f,0.f,0.f,0.f};
  float4 vA1 = {0.f,0.f,0.f,0.f}, vB1 = {0.f,0.f,0.f,0.f};
  if (!uniform) {
    const float* vb0 = vsum + ((size_t)0 * CB + b) * COUT;
    vA0 = *(const float4*)(vb0 + 4 * g);
    vB0 = *(const float4*)(vb0 + 16 + 4 * g);
    const float* vb1 = vsum + ((size_t)1 * CB + b) * COUT;
    vA1 = *(const float4*)(vb1 + 4 * g);
    vB1 = *(const float4*)(vb1 + 16 + 4 * g);
  }

  float acc0A[4] = {0.f,0.f,0.f,0.f}, acc0B[4] = {0.f,0.f,0.f,0.f};
  float acc1A[4] = {0.f,0.f,0.f,0.f}, acc1B[4] = {0.f,0.f,0.f,0.f};
  float esum0 = 0.f, esum1 = 0.f;

#pragma unroll
  for (int ri = 0; ri < RC; ++ri) {
    h4t xr = xrow[ri * 512];     // 8 B coalesced (512 B/wave contiguous)
    h8 bx = {xr[0], xr[1], xr[2], xr[3],
             (_Float16)0.f, (_Float16)0.f, (_Float16)0.f, (_Float16)0.f};
    h8 wf0 = w0row[ri * 64];
    h8 wf1 = w1row[ri * 64];
    h8 aA0 = {wf0[0], wf0[1], wf0[2], wf0[3],
              (_Float16)0.f, (_Float16)0.f, (_Float16)0.f, (_Float16)0.f};
    h8 aB0 = {wf0[4], wf0[5], wf0[6], wf0[7],
              (_Float16)0.f, (_Float16)0.f, (_Float16)0.f, (_Float16)0.f};
    h8 aA1 = {wf1[0], wf1[1], wf1[2], wf1[3],
              (_Float16)0.f, (_Float16)0.f, (_Float16)0.f, (_Float16)0.f};
    h8 aB1 = {wf1[4], wf1[5], wf1[6], wf1[7],
              (_Float16)0.f, (_Float16)0.f, (_Float16)0.f, (_Float16)0.f};
    f4 z = {0.f, 0.f, 0.f, 0.f};
    f4 pA0 = __builtin_amdgcn_mfma_f32_16x16x32_f16(aA0, bx, z, 0, 0, 0);
    f4 pB0 = __builtin_amdgcn_mfma_f32_16x16x32_f16(aB0, bx, z, 0, 0, 0);
    f4 pA1 = __builtin_amdgcn_mfma_f32_16x16x32_f16(aA1, bx, z, 0, 0, 0);
    f4 pB1 = __builtin_amdgcn_mfma_f32_16x16x32_f16(aB1, bx, z, 0, 0, 0);

    float e0 = 1.f, e1 = 1.f;
    if (!uniform) {
      float d0 = pA0[0]*vA0.x + pA0[1]*vA0.y + pA0[2]*vA0.z + pA0[3]*vA0.w
               + pB0[0]*vB0.x + pB0[1]*vB0.y + pB0[2]*vB0.z + pB0[3]*vB0.w;
      float d1 = pA1[0]*vA1.x + pA1[1]*vA1.y + pA1[2]*vA1.z + pA1[3]*vA1.w
               + pB1[0]*vB1.x + pB1[1]*vB1.y + pB1[2]*vB1.z + pB1[3]*vB1.w;
      d0 += __shfl_xor(d0, 16);  d1 += __shfl_xor(d1, 16);
      d0 += __shfl_xor(d0, 32);  d1 += __shfl_xor(d1, 32);
      e0 = __expf(d0);           e1 = __expf(d1);
    }
    esum0 += e0;  esum1 += e1;
#pragma unroll
    for (int j = 0; j < 4; ++j) {
      acc0A[j] += e0 * pA0[j];  acc0B[j] += e0 * pB0[j];
      acc1A[j] += e1 * pA1[j];  acc1B[j] += e1 * pB1[j];
    }
  }
  store_partials(partialA, partialE, acc0A, acc0B, esum0, 0, rch, t, g, b);
  store_partials(partialA, partialE, acc1A, acc1B, esum1, 1, rch, t, g, b);
}

// ---------------------------------------------------------------------------
// redv: per (c,b) reduce NRCH2 chunk-partials (fragment-order via idx
// permutation) -> v = squash(s/esum). mode: 0 vsum=v, 1 vsum+=v, 2 out=v.
// grid 256 x 256 threads. Proven structure (k-loop now 64).
// ---------------------------------------------------------------------------
__global__ __launch_bounds__(256) void caps_redv_kernel(
    const float* __restrict__ partialA, const float* __restrict__ partialE,
    float* __restrict__ vsum, float* __restrict__ out, int mode)
{
  const int cb = (int)blockIdx.x;
  const int c2 = cb >> 7, b2 = cb & 127;
  const int t  = (int)threadIdx.x;
  const int o = t & 31, jg = t >> 5;          // 8 j-groups
  const int wv2 = b2 >> 4, m2 = b2 & 15;
  const int half = o >> 4, oo = o & 15, g2 = oo >> 2, j2 = oo & 3;
  const size_t idx = (size_t)(wv2 * 64 + g2 * 16 + m2) * 8 + half * 4 + j2;

  __shared__ float red[8][33];
  __shared__ float rede[8];

  float s = 0.f;
#pragma unroll 8
  for (int k = 0; k < NRCH2 / 8; ++k) {
    const int j = jg + k * 8;
    s += partialA[((size_t)(c2 * NRCH2 + j)) * 4096 + idx];
  }
  red[jg][o] = s;
  __syncthreads();

  if (t < 8) {
    float e = 0.f;
#pragma unroll 8
    for (int k = 0; k < NRCH2 / 8; ++k)
      e += partialE[((size_t)(c2 * NRCH2 + t + k * 8)) * CB + b2];
    rede[t] = e;
  }
  __syncthreads();

  if (t < 32) {
    float sv = 0.f, es = 0.f;
#pragma unroll
    for (int jj = 0; jj < 8; ++jj) { sv += red[jj][t]; es += rede[jj]; }
    float sm = sv / es;
    float sn = sm * sm;
#pragma unroll
    for (int sh = 1; sh < 32; sh <<= 1) sn += __shfl_xor(sn, sh);
    float fac = sn / ((1.f + sn + EPSF) * sqrtf(sn + EPSF));
    float vv = sm * fac;
    if (mode == 2)      out[cb * COUT + t]  = vv;
    else if (mode == 1) vsum[cb * COUT + t] += vv;
    else                vsum[cb * COUT + t] = vv;
  }
}

extern "C" void kernel_launch(void* const* d_in, const int* in_sizes, int n_in,
                              void* d_out, int out_size, void* d_ws, size_t ws_size,
                              hipStream_t stream) {
  const float* x = (const float*)d_in[0];
  const float* w = (const float*)d_in[1];
  float* out = (float*)d_out;

  char* p = (char*)d_ws;
  h8* wp = (h8*)p;                                 // 2*4096*64*16B = 8,388,608 B
  p += (size_t)CCAP * CR * 64 * sizeof(h8);
  h4t* xq = (h4t*)p;                               // 4096*8*64*8B = 16,777,216 B
  p += (size_t)CR * 8 * 64 * sizeof(h4t);
  float* vsum = (float*)p;                         // 32,768 B
  p += (size_t)CCAP * CB * COUT * sizeof(float);
  float* partialA = (float*)p;                     // 2*512*4096*4 = 16,777,216 B
  p += (size_t)CCAP * NRCH2 * 4096 * sizeof(float);
  float* partialE = (float*)p;                     // 2*512*128*4 = 524,288 B
  // total ~42.5 MB (83.9 MB proven available)

  caps_prepw_kernel<<<dim3(CCAP * 1024), 256, 0, stream>>>(w, wp);
  caps_prepx_kernel<<<dim3(512), 256, 0, stream>>>(x, xq);
  caps_pass_kernel<<<dim3(NRCH2), 512, 0, stream>>>(
      xq, wp, vsum, partialA, partialE, 1);
  caps_redv_kernel<<<dim3(CCAP * CB), 256, 0, stream>>>(
      partialA, partialE, vsum, out, 0);
  caps_pass_kernel<<<dim3(NRCH2), 512, 0, stream>>>(
      xq, wp, vsum, partialA, partialE, 0);
  caps_redv_kernel<<<dim3(CCAP * CB), 256, 0, stream>>>(
      partialA, partialE, vsum, out, 1);
  caps_pass_kernel<<<dim3(NRCH2), 512, 0, stream>>>(
      xq, wp, vsum, partialA, partialE, 0);
  caps_redv_kernel<<<dim3(CCAP * CB), 256, 0, stream>>>(
      partialA, partialE, vsum, out, 2);
}

// Round 15
// 106.255 us; speedup vs baseline: 1.3537x; 1.3537x over previous
//
#include <hip/hip_runtime.h>
#include <math.h>

// CapsuleLayer dynamic routing, MI355X — R15: tiled-transpose x once (xq),
// prepack W once (wp), then 3 fully-coalesced LDS-free MFMA passes.
// B=128, R=4096, IN=16, OUT=32, C=2, 3 routing iterations.
//
// Evidence: R7(LDS W) == R13(global W) ~21us/pass -> invariant is the
// x-gather: each wave x-load touches 16 lines 256KB apart (b-major x),
// ~16 L2 requests/instr; request-rate arithmetic matches ~20us. R14 proved
// a NAIVE scatter prepx costs more than it saves; R15 does the transpose
// tiled through LDS (both sides coalesced). Pass reads become 8B/lane,
// 512B/wave contiguous for x and 1KB/wave for W. RC=8 -> 1024 blocks ->
// 4 blocks/CU TLP.
// Math (proven R5+): logits linear in running v-sum; it0 softmax uniform.
// k-slot safety (HW-verified R6+): both mfma operands put i=4*(L>>4)+j in
// elements 0..3, zeros 4..7. C/D layout (m89): col=lane&15, row=4g+reg.
// f16 precision proven (absmax 0.0039 < threshold 0.0124).
#define CB     128
#define CR     4096
#define CIN    16
#define COUT   32
#define CCAP   2
#define RC     8             // r rows per pass chunk
#define NRCH2  (CR / RC)     // 512 chunks per c
#define EPSF   1e-12f

typedef _Float16 h8  __attribute__((ext_vector_type(8)));
typedef _Float16 h4t __attribute__((ext_vector_type(4)));
typedef float    f4  __attribute__((ext_vector_type(4)));

// ---------------------------------------------------------------------------
// prepack W (proven R13/R14): wp[(c*CR + r)*64 + L] = h8 { W[c][r][4g+j][m],
//   W[c][r][4g+j][16+m] } (j=0..3), g=L>>4, m=L&15.
// ---------------------------------------------------------------------------
__global__ __launch_bounds__(256) void caps_prepw_kernel(
    const float* __restrict__ w, h8* __restrict__ wp)
{
  const int blk = (int)blockIdx.x;
  const int c   = blk >> 10;
  const int r0  = (blk & 1023) * 4;
  const int t   = (int)threadIdx.x;

  __shared__ __align__(16) float Wl[4 * 512];   // 8 KB
  {
    const float4* src = (const float4*)(w + ((size_t)c * CR + r0) * 512);
    ((float4*)Wl)[t]       = src[t];
    ((float4*)Wl)[t + 256] = src[t + 256];
  }
  __syncthreads();

  const int rr = t >> 6;        // 0..3
  const int L  = t & 63;
  const int g  = L >> 4, m = L & 15;
  h8 v;
#pragma unroll
  for (int j = 0; j < 4; ++j) {
    v[j]     = (_Float16)Wl[rr * 512 + (4 * g + j) * 32 + m];
    v[4 + j] = (_Float16)Wl[rr * 512 + (4 * g + j) * 32 + 16 + m];
  }
  wp[((size_t)c * CR + r0 + rr) * 64 + L] = v;
}

// ---------------------------------------------------------------------------
// prepx v2 — TILED transpose x -> B-fragment order f16:
//   xq[(r*8 + wv)*64 + g*16 + m] = h4 { x[wv*16+m][r][4g+j] }  j=0..3
// grid = 8 wv-groups x 64 r-chunks = 512 blocks x 256 threads.
// Read side: 16 b-rows x 64 r x 64B, contiguous 4KB per b-row, coalesced.
// Write side: complete 512B records, 128B contiguous per thread.
// LDS tile padded [16][65][17] f32 to spread bank access.
// ---------------------------------------------------------------------------
#define XL(bb, rr_, ii) ((bb) * 1105 + (rr_) * 17 + (ii))
__global__ __launch_bounds__(256) void caps_prepx_kernel(
    const float* __restrict__ x, h4t* __restrict__ xq)
{
  const int blk = (int)blockIdx.x;
  const int wv  = blk >> 6;          // 0..7
  const int rch = blk & 63;          // 0..63
  const int r0  = rch * 64;
  const int t   = (int)threadIdx.x;

  __shared__ float Xl[16 * 65 * 17];   // 70,720 B

  // ---- read phase: thread t -> b-row (t>>4), chunk (t&15); 16 float4 ----
  {
    const int brow = t >> 4, chunk = t & 15;
    const float4* src = (const float4*)(
        x + ((size_t)(wv * 16 + brow)) * CR * CIN + (size_t)r0 * CIN);
#pragma unroll
    for (int k = 0; k < 16; ++k) {
      const int fi = chunk + k * 16;       // 0..255 float4 within row-slice
      float4 v = src[fi];
      const int rl = fi >> 2, iq = fi & 3;
      float* d = &Xl[XL(brow, rl, iq * 4)];
      d[0] = v.x; d[1] = v.y; d[2] = v.z; d[3] = v.w;
    }
  }
  __syncthreads();

  // ---- write phase: thread t -> (r_local = t>>2, g = t&3); 16 m-records --
  {
    const int rl = t >> 2, g = t & 3;
    h4t recs[16];
#pragma unroll
    for (int m = 0; m < 16; ++m) {
      recs[m] = h4t{(_Float16)Xl[XL(m, rl, 4 * g + 0)],
                    (_Float16)Xl[XL(m, rl, 4 * g + 1)],
                    (_Float16)Xl[XL(m, rl, 4 * g + 2)],
                    (_Float16)Xl[XL(m, rl, 4 * g + 3)]};
    }
    h4t* dst = xq + ((size_t)(r0 + rl) * 8 + wv) * 64 + g * 16;
#pragma unroll
    for (int m = 0; m < 16; ++m) dst[m] = recs[m];
  }
}

// direct fragment-order partial stores (coalesced, no barriers). Proven.
__device__ __forceinline__ void store_partials(float* __restrict__ partialA,
                                               float* __restrict__ partialE,
                                               const float* accA, const float* accB,
                                               float esum, int c, int rch,
                                               int t, int g, int b)
{
  float4 a4 = {accA[0], accA[1], accA[2], accA[3]};
  float4 b4 = {accB[0], accB[1], accB[2], accB[3]};
  float* dst = partialA + ((size_t)(c * NRCH2 + rch)) * 4096 + (size_t)t * 8;
  *(float4*)dst = a4;
  *(float4*)(dst + 4) = b4;
  if (g == 0) partialE[((size_t)(c * NRCH2 + rch)) * CB + b] = esum;
}

// ---------------------------------------------------------------------------
// pass (R13 shape, xq source): grid = C*NRCH2 = 1024 blocks x 512 threads.
// Zero LDS, zero barriers. Per ri: 1 xq h4 (8B, 512B/wave contiguous) +
// 1 wp h8 (16B, 1KB/wave contiguous) -> 2 mfma -> dot+2 shfl+exp -> acc.
// ---------------------------------------------------------------------------
__global__ __launch_bounds__(512, 4) void caps_pass_kernel(
    const h4t* __restrict__ xq, const h8* __restrict__ wp,
    const float* __restrict__ vsum,
    float* __restrict__ partialA, float* __restrict__ partialE,
    int uniform)
{
  const int blk = (int)blockIdx.x;
  const int c = blk >> 9, rch = blk & 511;
  const int r0 = rch * RC;
  const int t = (int)threadIdx.x;
  const int wv = t >> 6, L = t & 63, g = L >> 4, m = L & 15;
  const int b  = wv * 16 + m;

  const h4t* xrow = xq + ((size_t)(r0 * 8 + wv)) * 64 + L;
  const h8*  wrow = wp + ((size_t)c * CR + r0) * 64 + L;

  float4 vA = {0.f, 0.f, 0.f, 0.f}, vB = {0.f, 0.f, 0.f, 0.f};
  if (!uniform) {
    const float* vb = vsum + ((size_t)c * CB + b) * COUT;
    vA = *(const float4*)(vb + 4 * g);
    vB = *(const float4*)(vb + 16 + 4 * g);
  }

  float accA[4] = {0.f, 0.f, 0.f, 0.f};
  float accB[4] = {0.f, 0.f, 0.f, 0.f};
  float esum = 0.f;

#pragma unroll
  for (int ri = 0; ri < RC; ++ri) {
    h4t xr = xrow[ri * 512];     // (r+1) record stride = 8*64 h4
    h8 bx = {xr[0], xr[1], xr[2], xr[3],
             (_Float16)0.f, (_Float16)0.f, (_Float16)0.f, (_Float16)0.f};
    h8 wf = wrow[ri * 64];
    h8 aA = {wf[0], wf[1], wf[2], wf[3],
             (_Float16)0.f, (_Float16)0.f, (_Float16)0.f, (_Float16)0.f};
    h8 aB = {wf[4], wf[5], wf[6], wf[7],
             (_Float16)0.f, (_Float16)0.f, (_Float16)0.f, (_Float16)0.f};
    f4 z = {0.f, 0.f, 0.f, 0.f};
    f4 pA = __builtin_amdgcn_mfma_f32_16x16x32_f16(aA, bx, z, 0, 0, 0);
    f4 pB = __builtin_amdgcn_mfma_f32_16x16x32_f16(aB, bx, z, 0, 0, 0);

    float e = 1.f;                 // it0: softmax over zero logits
    if (!uniform) {
      float d = pA[0] * vA.x + pA[1] * vA.y + pA[2] * vA.z + pA[3] * vA.w
              + pB[0] * vB.x + pB[1] * vB.y + pB[2] * vB.z + pB[3] * vB.w;
      d += __shfl_xor(d, 16);
      d += __shfl_xor(d, 32);
      e = __expf(d);               // safe: |d| <= ||p_row|| * ||vsum|| < ~80
    }
    esum += e;
#pragma unroll
    for (int j = 0; j < 4; ++j) { accA[j] += e * pA[j]; accB[j] += e * pB[j]; }
  }
  store_partials(partialA, partialE, accA, accB, esum, c, rch, t, g, b);
}

// ---------------------------------------------------------------------------
// redv (R14-proven, NRCH2=512): per (c,b) reduce chunk-partials
// (fragment-order via idx permutation) -> v = squash(s/esum).
// mode: 0 vsum=v, 1 vsum+=v, 2 out=v. grid 256 x 256 threads.
// ---------------------------------------------------------------------------
__global__ __launch_bounds__(256) void caps_redv_kernel(
    const float* __restrict__ partialA, const float* __restrict__ partialE,
    float* __restrict__ vsum, float* __restrict__ out, int mode)
{
  const int cb = (int)blockIdx.x;
  const int c2 = cb >> 7, b2 = cb & 127;
  const int t  = (int)threadIdx.x;
  const int o = t & 31, jg = t >> 5;          // 8 j-groups
  const int wv2 = b2 >> 4, m2 = b2 & 15;
  const int half = o >> 4, oo = o & 15, g2 = oo >> 2, j2 = oo & 3;
  const size_t idx = (size_t)(wv2 * 64 + g2 * 16 + m2) * 8 + half * 4 + j2;

  __shared__ float red[8][33];
  __shared__ float rede[8];

  float s = 0.f;
#pragma unroll 8
  for (int k = 0; k < NRCH2 / 8; ++k) {
    const int j = jg + k * 8;
    s += partialA[((size_t)(c2 * NRCH2 + j)) * 4096 + idx];
  }
  red[jg][o] = s;
  __syncthreads();

  if (t < 8) {
    float e = 0.f;
#pragma unroll 8
    for (int k = 0; k < NRCH2 / 8; ++k)
      e += partialE[((size_t)(c2 * NRCH2 + t + k * 8)) * CB + b2];
    rede[t] = e;
  }
  __syncthreads();

  if (t < 32) {
    float sv = 0.f, es = 0.f;
#pragma unroll
    for (int jj = 0; jj < 8; ++jj) { sv += red[jj][t]; es += rede[jj]; }
    float sm = sv / es;
    float sn = sm * sm;
#pragma unroll
    for (int sh = 1; sh < 32; sh <<= 1) sn += __shfl_xor(sn, sh);
    float fac = sn / ((1.f + sn + EPSF) * sqrtf(sn + EPSF));
    float vv = sm * fac;
    if (mode == 2)      out[cb * COUT + t]  = vv;
    else if (mode == 1) vsum[cb * COUT + t] += vv;
    else                vsum[cb * COUT + t] = vv;
  }
}

extern "C" void kernel_launch(void* const* d_in, const int* in_sizes, int n_in,
                              void* d_out, int out_size, void* d_ws, size_t ws_size,
                              hipStream_t stream) {
  const float* x = (const float*)d_in[0];
  const float* w = (const float*)d_in[1];
  float* out = (float*)d_out;

  char* p = (char*)d_ws;
  h8* wp = (h8*)p;                                 // 2*4096*64*16B = 8,388,608 B
  p += (size_t)CCAP * CR * 64 * sizeof(h8);
  h4t* xq = (h4t*)p;                               // 4096*8*64*8B = 16,777,216 B
  p += (size_t)CR * 8 * 64 * sizeof(h4t);
  float* vsum = (float*)p;                         // 32,768 B
  p += (size_t)CCAP * CB * COUT * sizeof(float);
  float* partialA = (float*)p;                     // 2*512*4096*4 = 16,777,216 B
  p += (size_t)CCAP * NRCH2 * 4096 * sizeof(float);
  float* partialE = (float*)p;                     // 2*512*128*4 = 524,288 B
  // total ~42.5 MB (83.9 MB proven available)

  caps_prepw_kernel<<<dim3(CCAP * 1024), 256, 0, stream>>>(w, wp);
  caps_prepx_kernel<<<dim3(512), 256, 0, stream>>>(x, xq);
  caps_pass_kernel<<<dim3(CCAP * NRCH2), 512, 0, stream>>>(
      xq, wp, vsum, partialA, partialE, 1);
  caps_redv_kernel<<<dim3(CCAP * CB), 256, 0, stream>>>(
      partialA, partialE, vsum, out, 0);
  caps_pass_kernel<<<dim3(CCAP * NRCH2), 512, 0, stream>>>(
      xq, wp, vsum, partialA, partialE, 0);
  caps_redv_kernel<<<dim3(CCAP * CB), 256, 0, stream>>>(
      partialA, partialE, vsum, out, 1);
  caps_pass_kernel<<<dim3(CCAP * NRCH2), 512, 0, stream>>>(
      xq, wp, vsum, partialA, partialE, 0);
  caps_redv_kernel<<<dim3(CCAP * CB), 256, 0, stream>>>(
      partialA, partialE, vsum, out, 2);
}